// Round 1
// baseline (78.182 us; speedup 1.0000x reference)
//
#include <hip/hip_runtime.h>

#define HW    56
#define CH    64
#define BATCH 4
#define KS    7
#define PAD   3
#define PIX   (HW*HW)        // 3136
#define NPIX  (BATCH*PIX)    // 12544
#define HALO  14             // 8 + 2*3
#define HP    (HALO*HALO)    // 196
#define PC    65             // padded leading dim for LDS tiles

// ---------------- Kernel A: q,k,v = 1x1 conv (three 64x64 GEMMs) -------------
// grid 196 (= 4 batches * 49 pixel-chunks of 64), block 512.
__global__ __launch_bounds__(512) void qkv_kernel(
    const float* __restrict__ x,  const float* __restrict__ Wq,
    const float* __restrict__ Wk, const float* __restrict__ Wv,
    float* __restrict__ qg, float* __restrict__ kg, float* __restrict__ vg)
{
    __shared__ float xs[CH * 64];           // [ci][px]
    const int t   = threadIdx.x;
    const int blk = blockIdx.x;
    const int b   = blk / 49;
    const int hw0 = (blk % 49) * 64;

    for (int idx = t; idx < CH * 64; idx += 512) {
        int ci = idx >> 6, px = idx & 63;
        xs[ci * 64 + px] = x[(b * CH + ci) * PIX + hw0 + px];
    }
    __syncthreads();

    const int px = t & 63;
    const int w  = __builtin_amdgcn_readfirstlane(t >> 6);   // wave id 0..7 (uniform)

    for (int j = 0; j < 8; ++j) {
        const int co = w * 8 + j;                            // wave-uniform -> s_loads for W
        float aq = 0.f, ak = 0.f, av = 0.f;
        #pragma unroll
        for (int ci = 0; ci < CH; ++ci) {
            float xv = xs[ci * 64 + px];
            aq += Wq[co * CH + ci] * xv;
            ak += Wk[co * CH + ci] * xv;
            av += Wv[co * CH + ci] * xv;
        }
        const int o = (b * CH + co) * PIX + hw0 + px;
        qg[o] = aq; kg[o] = ak; vg[o] = av;
    }
}

// ---------------- Kernel B: windowed per-channel attention -------------------
// grid 196 (= 4 batches * 7*7 tiles of 8x8), block 512.
__global__ __launch_bounds__(512) void attn_kernel(
    const float* __restrict__ qg, const float* __restrict__ kg,
    const float* __restrict__ vg, const float* __restrict__ rel_h,
    const float* __restrict__ rel_w, float* __restrict__ out)
{
    __shared__ float ks[HP * PC];   // [halo_pixel][c]
    __shared__ float vs[HP * PC];
    __shared__ float qs[64 * PC];   // [inner_pixel][c]

    const int t   = threadIdx.x;
    const int blk = blockIdx.x;
    const int b   = blk / 49;
    const int t49 = blk % 49;
    const int ty0 = (t49 / 7) * 8;
    const int tx0 = (t49 % 7) * 8;

    // stage k,v halo (zero outside the image)
    for (int idx = t; idx < HP * CH; idx += 512) {
        int c  = idx / HP;
        int p  = idx - c * HP;
        int hy = ty0 + p / HALO - PAD;
        int hx = tx0 + p % HALO - PAD;
        bool ok = (hy >= 0) && (hy < HW) && (hx >= 0) && (hx < HW);
        int g = ((b * CH + c) * HW + hy) * HW + hx;
        ks[p * PC + c] = ok ? kg[g] : 0.f;
        vs[p * PC + c] = ok ? vg[g] : 0.f;
    }
    // stage q (inner 8x8)
    for (int idx = t; idx < 64 * CH; idx += 512) {
        int c = idx >> 6, ip = idx & 63;
        qs[ip * PC + c] =
            qg[((b * CH + c) * HW + ty0 + (ip >> 3)) * HW + tx0 + (ip & 7)];
    }
    __syncthreads();

    const int c = t & 63;
    const int g = t >> 6;           // 0..7, wave-uniform
    const bool is_h = (c < 32);

    float relv[KS];
    #pragma unroll
    for (int j = 0; j < KS; ++j)
        relv[j] = is_h ? rel_h[c * KS + j] : rel_w[(c - 32) * KS + j];

    for (int i = 0; i < 8; ++i) {
        const int ip = i * 8 + g;           // oy = i, ox = g  (wave-uniform pixel)
        const int oy = ip >> 3, ox = ip & 7;
        const float qv = qs[ip * PC + c];

        float s[KS * KS];
        float m = -1e30f;
        #pragma unroll
        for (int kh = 0; kh < KS; ++kh) {
            const int prow = (oy + kh) * HALO + ox;
            #pragma unroll
            for (int kw = 0; kw < KS; ++kw) {
                float kv = ks[(prow + kw) * PC + c];
                float sc = qv * kv;
                s[kh * KS + kw] = sc;
                m = fmaxf(m, sc);
            }
        }
        float sum = 0.f, acc = 0.f;
        #pragma unroll
        for (int kh = 0; kh < KS; ++kh) {
            const int prow = (oy + kh) * HALO + ox;
            #pragma unroll
            for (int kw = 0; kw < KS; ++kw) {
                float e  = __expf(s[kh * KS + kw] - m);
                float vv = vs[(prow + kw) * PC + c] + (is_h ? relv[kh] : relv[kw]);
                sum += e;
                acc += e * vv;
            }
        }
        out[((b * CH + c) * HW + ty0 + oy) * HW + tx0 + ox] = acc / sum;
    }
}

// ---------------- Fallback: naive fused kernel (if ws too small) -------------
__global__ __launch_bounds__(256) void naive_kernel(
    const float* __restrict__ x,  const float* __restrict__ Wq,
    const float* __restrict__ Wk, const float* __restrict__ Wv,
    const float* __restrict__ rel_h, const float* __restrict__ rel_w,
    float* __restrict__ out)
{
    int idx = blockIdx.x * 256 + threadIdx.x;
    if (idx >= BATCH * CH * PIX) return;
    int wpx = idx % HW;
    int hpx = (idx / HW) % HW;
    int c   = (idx / PIX) % CH;
    int b   = idx / (PIX * CH);
    const float* xb = x + (size_t)b * CH * PIX;

    float q = 0.f;
    for (int ci = 0; ci < CH; ++ci)
        q += Wq[c * CH + ci] * xb[ci * PIX + hpx * HW + wpx];

    float s[KS * KS];
    float m = -1e30f;
    #pragma unroll
    for (int kh = 0; kh < KS; ++kh)
        #pragma unroll
        for (int kw = 0; kw < KS; ++kw) {
            int y = hpx + kh - PAD, xx = wpx + kw - PAD;
            float kv = 0.f;
            if (y >= 0 && y < HW && xx >= 0 && xx < HW)
                for (int ci = 0; ci < CH; ++ci)
                    kv += Wk[c * CH + ci] * xb[ci * PIX + y * HW + xx];
            float sc = q * kv;
            s[kh * KS + kw] = sc;
            m = fmaxf(m, sc);
        }
    float sum = 0.f, acc = 0.f;
    #pragma unroll
    for (int kh = 0; kh < KS; ++kh)
        #pragma unroll
        for (int kw = 0; kw < KS; ++kw) {
            int y = hpx + kh - PAD, xx = wpx + kw - PAD;
            float vv = 0.f;
            if (y >= 0 && y < HW && xx >= 0 && xx < HW)
                for (int ci = 0; ci < CH; ++ci)
                    vv += Wv[c * CH + ci] * xb[ci * PIX + y * HW + xx];
            vv += (c < 32) ? rel_h[c * KS + kh] : rel_w[(c - 32) * KS + kw];
            float e = __expf(s[kh * KS + kw] - m);
            sum += e;
            acc += e * vv;
        }
    out[idx] = acc / sum;
}

extern "C" void kernel_launch(void* const* d_in, const int* in_sizes, int n_in,
                              void* d_out, int out_size, void* d_ws, size_t ws_size,
                              hipStream_t stream) {
    const float* x     = (const float*)d_in[0];
    const float* Wq    = (const float*)d_in[1];
    const float* Wk    = (const float*)d_in[2];
    const float* Wv    = (const float*)d_in[3];
    const float* rel_h = (const float*)d_in[4];
    const float* rel_w = (const float*)d_in[5];
    float* out = (float*)d_out;

    const size_t arr  = (size_t)BATCH * CH * PIX;      // 802816 floats
    const size_t need = 3 * arr * sizeof(float);       // ~9.6 MB

    if (ws_size >= need) {
        float* qg = (float*)d_ws;
        float* kg = qg + arr;
        float* vg = kg + arr;
        qkv_kernel<<<196, 512, 0, stream>>>(x, Wq, Wk, Wv, qg, kg, vg);
        attn_kernel<<<196, 512, 0, stream>>>(qg, kg, vg, rel_h, rel_w, out);
    } else {
        naive_kernel<<<(BATCH * CH * PIX + 255) / 256, 256, 0, stream>>>(
            x, Wq, Wk, Wv, rel_h, rel_w, out);
    }
}

// Round 2
// 45.890 us; speedup vs baseline: 1.7037x; 1.7037x over previous
//
#include <hip/hip_runtime.h>

#define HW    56
#define CH    64
#define BATCH 4
#define KS    7
#define PAD   3
#define PIX   (HW*HW)        // 3136
#define NPIX  (BATCH*PIX)    // 12544

// ---------------- Kernel A: q,k,v = 1x1 conv, output layout [b][hw][c] ------
// grid 588 = 3 mats * 4 b * 49 chunks(64 px), block 256 (4 waves).
__global__ __launch_bounds__(256) void qkv_kernel(
    const float* __restrict__ x,  const float* __restrict__ Wq,
    const float* __restrict__ Wk, const float* __restrict__ Wv,
    float* __restrict__ qg, float* __restrict__ kg, float* __restrict__ vg)
{
    __shared__ float xs[64][68];    // [px][ci], 68 keeps 16B alignment
    __shared__ float wsT[64][65];   // [ci][co]
    const int t   = threadIdx.x;
    const int mat = blockIdx.x / 196;
    const int rem = blockIdx.x % 196;
    const int b   = rem / 49;
    const int hw0 = (rem % 49) * 64;

    const float* __restrict__ W    = (mat == 0) ? Wq : (mat == 1) ? Wk : Wv;
    float*       __restrict__ outp = (mat == 0) ? qg : (mat == 1) ? kg : vg;

    #pragma unroll
    for (int k = 0; k < 16; ++k) {          // weights: coalesced read, xposed write
        int idx = t + k * 256;
        wsT[idx & 63][idx >> 6] = W[idx];
    }
    #pragma unroll
    for (int k = 0; k < 16; ++k) {          // x tile: coalesced read
        int idx = t + k * 256;
        int ci = idx >> 6, px = idx & 63;
        xs[px][ci] = x[(b * CH + ci) * PIX + hw0 + px];
    }
    __syncthreads();

    const int c   = t & 63;                 // lane = output channel
    const int grp = t >> 6;                 // 4 groups x 16 px
    float w[64];
    #pragma unroll
    for (int ci = 0; ci < 64; ++ci) w[ci] = wsT[ci][c];   // conflict-free

    #pragma unroll
    for (int i = 0; i < 16; ++i) {
        const int px = grp * 16 + i;        // wave-uniform
        float a0 = 0.f, a1 = 0.f;
        #pragma unroll
        for (int ci = 0; ci < 64; ci += 4) {
            float4 xv = *(const float4*)&xs[px][ci];      // broadcast b128
            a0 = fmaf(w[ci],     xv.x, a0);
            a1 = fmaf(w[ci + 1], xv.y, a1);
            a0 = fmaf(w[ci + 2], xv.z, a0);
            a1 = fmaf(w[ci + 3], xv.w, a1);
        }
        outp[(b * PIX + hw0 + px) * 64 + c] = a0 + a1;    // coalesced
    }
}

// ---------------- Kernel B: windowed per-channel attention ------------------
// grid 392 = 4 b * (7x14 tiles of 8x4), block 512 (8 waves).
#define TW 4
#define TH 8
#define HALOW 10
#define HALOH 14
#define HP (HALOW*HALOH)   // 140

__global__ __launch_bounds__(512) void attn_kernel(
    const float* __restrict__ qT, const float* __restrict__ kT,
    const float* __restrict__ vT, const float* __restrict__ rel_h,
    const float* __restrict__ rel_w, float* __restrict__ out)
{
    __shared__ float2 kvs[HP][66];   // {k,v} packed -> one ds_read_b64 per tap
    const int t    = threadIdx.x;
    const int b    = blockIdx.x / 98;
    const int tile = blockIdx.x % 98;
    const int ty0  = (tile / 14) * TH;
    const int tx0  = (tile % 14) * TW;

    for (int idx = t; idx < HP * 64; idx += 512) {
        int c  = idx & 63, p = idx >> 6;
        int hy = ty0 + p / HALOW - PAD;
        int hx = tx0 + p % HALOW - PAD;
        bool ok = (hy >= 0) & (hy < HW) & (hx >= 0) & (hx < HW);
        int g = (b * PIX + hy * HW + hx) * 64 + c;        // coalesced (lanes vary c)
        float kv = ok ? kT[g] : 0.f;
        float vv = ok ? vT[g] : 0.f;
        kvs[p][c] = make_float2(kv, vv);
    }
    __syncthreads();

    const int c  = t & 63;
    const int oy = t >> 6;               // 0..7, wave-uniform
    const bool is_h = (c < 32);
    float relv[KS];
    #pragma unroll
    for (int j = 0; j < KS; ++j)
        relv[j] = is_h ? rel_h[c * KS + j] : rel_w[(c - 32) * KS + j];

    float res[TW];
    #pragma unroll
    for (int ox = 0; ox < TW; ++ox) {
        const float qv = qT[(b * PIX + (ty0 + oy) * HW + tx0 + ox) * 64 + c];
        float sum = 0.f, acc = 0.f;
        #pragma unroll
        for (int kh = 0; kh < KS; ++kh) {
            const int base = (oy + kh) * HALOW + ox;
            const float rh = relv[kh];
            #pragma unroll
            for (int kw = 0; kw < KS; ++kw) {
                float2 kv = kvs[base + kw][c];
                float e = __expf(qv * kv.x);              // no max pass needed
                sum += e;
                acc = fmaf(e, kv.y + (is_h ? rh : relv[kw]), acc);
            }
        }
        res[ox] = acc / sum;
    }

    // LDS transpose so the (B,C,H,W) store has 16B-contiguous runs
    __syncthreads();
    float* os = (float*)&kvs[0][0];      // reuse (all reads done)
    #pragma unroll
    for (int ox = 0; ox < TW; ++ox)
        os[(oy * TW + ox) * 66 + c] = res[ox];
    __syncthreads();
    #pragma unroll
    for (int k2 = 0; k2 < 4; ++k2) {
        int idx = t + k2 * 512;
        int cc = idx >> 5, p = idx & 31;
        out[((b * CH + cc) * HW + ty0 + (p >> 2)) * HW + tx0 + (p & 3)] =
            os[p * 66 + cc];
    }
}

// ---------------- Fallback: naive fused kernel (if ws too small) -------------
__global__ __launch_bounds__(256) void naive_kernel(
    const float* __restrict__ x,  const float* __restrict__ Wq,
    const float* __restrict__ Wk, const float* __restrict__ Wv,
    const float* __restrict__ rel_h, const float* __restrict__ rel_w,
    float* __restrict__ out)
{
    int idx = blockIdx.x * 256 + threadIdx.x;
    if (idx >= BATCH * CH * PIX) return;
    int wpx = idx % HW;
    int hpx = (idx / HW) % HW;
    int c   = (idx / PIX) % CH;
    int b   = idx / (PIX * CH);
    const float* xb = x + (size_t)b * CH * PIX;

    float q = 0.f;
    for (int ci = 0; ci < CH; ++ci)
        q += Wq[c * CH + ci] * xb[ci * PIX + hpx * HW + wpx];

    float sum = 0.f, acc = 0.f;
    #pragma unroll
    for (int kh = 0; kh < KS; ++kh)
        #pragma unroll
        for (int kw = 0; kw < KS; ++kw) {
            int y = hpx + kh - PAD, xx = wpx + kw - PAD;
            float kv = 0.f, vv = 0.f;
            if (y >= 0 && y < HW && xx >= 0 && xx < HW)
                for (int ci = 0; ci < CH; ++ci) {
                    float xvv = xb[ci * PIX + y * HW + xx];
                    kv += Wk[c * CH + ci] * xvv;
                    vv += Wv[c * CH + ci] * xvv;
                }
            vv += (c < 32) ? rel_h[c * KS + kh] : rel_w[(c - 32) * KS + kw];
            float e = __expf(q * kv);
            sum += e;
            acc += e * vv;
        }
    out[idx] = acc / sum;
}

extern "C" void kernel_launch(void* const* d_in, const int* in_sizes, int n_in,
                              void* d_out, int out_size, void* d_ws, size_t ws_size,
                              hipStream_t stream) {
    const float* x     = (const float*)d_in[0];
    const float* Wq    = (const float*)d_in[1];
    const float* Wk    = (const float*)d_in[2];
    const float* Wv    = (const float*)d_in[3];
    const float* rel_h = (const float*)d_in[4];
    const float* rel_w = (const float*)d_in[5];
    float* out = (float*)d_out;

    const size_t arr  = (size_t)NPIX * CH;             // 802816 floats
    const size_t need = 3 * arr * sizeof(float);       // ~9.6 MB

    if (ws_size >= need) {
        float* qg = (float*)d_ws;
        float* kg = qg + arr;
        float* vg = kg + arr;
        qkv_kernel<<<588, 256, 0, stream>>>(x, Wq, Wk, Wv, qg, kg, vg);
        attn_kernel<<<392, 512, 0, stream>>>(qg, kg, vg, rel_h, rel_w, out);
    } else {
        naive_kernel<<<(BATCH * CH * PIX + 255) / 256, 256, 0, stream>>>(
            x, Wq, Wk, Wv, rel_h, rel_w, out);
    }
}

// Round 3
// 44.236 us; speedup vs baseline: 1.7674x; 1.0374x over previous
//
#include <hip/hip_runtime.h>
#include <stdint.h>

#define HW    56
#define CH    64
#define BATCH 4
#define KS    7
#define PAD   3
#define PIX   (HW*HW)        // 3136
#define NPIX  (BATCH*PIX)    // 12544

typedef __attribute__((ext_vector_type(8))) short short8;
typedef __attribute__((ext_vector_type(4))) float f32x4;

// round-to-nearest-even fp32 -> bf16 bits
__device__ __forceinline__ uint32_t rne_bf16(float v) {
    uint32_t u = __float_as_uint(v);
    return (u + 0x7FFFu + ((u >> 16) & 1u)) >> 16;
}

// ------------- Kernel A: q,k,v = 1x1 conv via split-bf16 MFMA ---------------
// grid 196 (= 4 b * 49 chunks of 64 px), block 256 (4 waves).
// out layout: [b][px][c] fp32 (attn-friendly).
__global__ __launch_bounds__(256) void qkv_mfma(
    const float* __restrict__ x,  const float* __restrict__ Wq,
    const float* __restrict__ Wk, const float* __restrict__ Wv,
    float* __restrict__ qg, float* __restrict__ kg, float* __restrict__ vg)
{
    __shared__ short Ah[64][72], Al[64][72];   // [px][ci], 144B rows (16B-aligned)
    __shared__ short Bh[64][72], Bl[64][72];   // [co][ci]

    const int t   = threadIdx.x;
    const int b   = blockIdx.x / 49;
    const int hw0 = (blockIdx.x % 49) * 64;

    // ---- stage A = x^T tile (hi/lo bf16), coalesced global reads ----
    #pragma unroll
    for (int i = 0; i < 16; ++i) {
        int idx = t + i * 256;
        int px = idx & 63, ci = idx >> 6;
        float v  = x[(b * CH + ci) * PIX + hw0 + px];
        uint32_t h = rne_bf16(v);
        float hf = __uint_as_float(h << 16);
        uint32_t lo = rne_bf16(v - hf);
        Ah[px][ci] = (short)h;
        Al[px][ci] = (short)lo;
    }

    auto stageB = [&](const float* __restrict__ Wm) {
        #pragma unroll
        for (int i = 0; i < 16; ++i) {
            int idx = t + i * 256;
            int ci = idx & 63, co = idx >> 6;        // lanes vary ci: coalesced
            float v  = Wm[co * 64 + ci];
            uint32_t h = rne_bf16(v);
            float hf = __uint_as_float(h << 16);
            uint32_t lo = rne_bf16(v - hf);
            Bh[co][ci] = (short)h;                   // contiguous write: no conflict
            Bl[co][ci] = (short)lo;
        }
    };

    stageB(Wq);
    __syncthreads();

    const int l    = t & 63;
    const int w    = t >> 6;                 // wave = px-tile 0..3
    const int arow = w * 16 + (l & 15);
    const int koff = (l >> 4) * 8;
    const int prow = w * 16 + ((l >> 4) << 2);
    const int col  = l & 15;

    // A fragments (reused across all 3 mats)
    short8 a_h0 = *(const short8*)&Ah[arow][koff];
    short8 a_l0 = *(const short8*)&Al[arow][koff];
    short8 a_h1 = *(const short8*)&Ah[arow][32 + koff];
    short8 a_l1 = *(const short8*)&Al[arow][32 + koff];

    auto computeStore = [&](float* __restrict__ outp) {
        #pragma unroll
        for (int cot = 0; cot < 4; ++cot) {
            const int bco = cot * 16 + col;
            short8 bh0 = *(const short8*)&Bh[bco][koff];
            short8 bl0 = *(const short8*)&Bl[bco][koff];
            short8 bh1 = *(const short8*)&Bh[bco][32 + koff];
            short8 bl1 = *(const short8*)&Bl[bco][32 + koff];
            f32x4 a = {0.f, 0.f, 0.f, 0.f};
            a = __builtin_amdgcn_mfma_f32_16x16x32_bf16(a_l0, bh0, a, 0, 0, 0);
            a = __builtin_amdgcn_mfma_f32_16x16x32_bf16(a_h0, bl0, a, 0, 0, 0);
            a = __builtin_amdgcn_mfma_f32_16x16x32_bf16(a_h0, bh0, a, 0, 0, 0);
            a = __builtin_amdgcn_mfma_f32_16x16x32_bf16(a_l1, bh1, a, 0, 0, 0);
            a = __builtin_amdgcn_mfma_f32_16x16x32_bf16(a_h1, bl1, a, 0, 0, 0);
            a = __builtin_amdgcn_mfma_f32_16x16x32_bf16(a_h1, bh1, a, 0, 0, 0);
            const int co = cot * 16 + col;
            #pragma unroll
            for (int r = 0; r < 4; ++r)
                outp[(size_t)(b * PIX + hw0 + prow + r) * 64 + co] = a[r];
        }
    };

    computeStore(qg);
    __syncthreads();
    stageB(Wk);
    __syncthreads();
    computeStore(kg);
    __syncthreads();
    stageB(Wv);
    __syncthreads();
    computeStore(vg);
}

// ------------- Kernel B: windowed per-channel attention ---------------------
// grid 784 (= 4 b * 14*14 tiles of 4x4), block 256 (4 waves).
#define TW 4
#define TH 4
#define HALOW 10
#define HP  (HALOW*HALOW)   // 100

__global__ __launch_bounds__(256) void attn_kernel(
    const float* __restrict__ qT, const float* __restrict__ kT,
    const float* __restrict__ vT, const float* __restrict__ rel_h,
    const float* __restrict__ rel_w, float* __restrict__ out)
{
    __shared__ float2 kvs[HP][66];   // {k,v} packed, 52.8 KB -> 3 blocks/CU

    const int t    = threadIdx.x;
    const int b    = blockIdx.x / 196;
    const int tile = blockIdx.x % 196;
    const int ty0  = (tile / 14) * TH;
    const int tx0  = (tile % 14) * TW;
    const int c    = t & 63;
    const int oy   = t >> 6;               // 0..3, wave-uniform

    // q loads issued early (independent of LDS staging)
    float qv[TW];
    #pragma unroll
    for (int ox = 0; ox < TW; ++ox)
        qv[ox] = qT[(b * PIX + (ty0 + oy) * HW + tx0 + ox) * 64 + c];

    const bool is_h = (c < 32);
    float relv[KS];
    #pragma unroll
    for (int j = 0; j < KS; ++j)
        relv[j] = is_h ? rel_h[c * KS + j] : rel_w[(c - 32) * KS + j];

    for (int idx = t; idx < HP * 64; idx += 256) {
        int cc = idx & 63, p = idx >> 6;
        int hy = ty0 + p / HALOW - PAD;
        int hx = tx0 + p % HALOW - PAD;
        bool ok = (hy >= 0) & (hy < HW) & (hx >= 0) & (hx < HW);
        int g = (b * PIX + hy * HW + hx) * 64 + cc;   // lanes vary cc: coalesced
        float kvx = ok ? kT[g] : 0.f;
        float vvx = ok ? vT[g] : 0.f;
        kvs[p][cc] = make_float2(kvx, vvx);
    }
    __syncthreads();

    float sum[TW] = {0.f, 0.f, 0.f, 0.f};
    float acc[TW] = {0.f, 0.f, 0.f, 0.f};
    #pragma unroll
    for (int kh = 0; kh < KS; ++kh) {
        float2 row[HALOW];                  // halo row loaded once, reused by 4 ox
        #pragma unroll
        for (int i = 0; i < HALOW; ++i)
            row[i] = kvs[(oy + kh) * HALOW + i][c];
        const float rh = relv[kh];
        #pragma unroll
        for (int ox = 0; ox < TW; ++ox) {
            #pragma unroll
            for (int kw = 0; kw < KS; ++kw) {
                float2 f = row[ox + kw];
                float e = __expf(qv[ox] * f.x);
                sum[ox] += e;
                acc[ox] = fmaf(e, f.y + (is_h ? rh : relv[kw]), acc[ox]);
            }
        }
    }

    // LDS transpose for a coalesced (B,C,H,W) store
    __syncthreads();
    float* os = (float*)&kvs[0][0];
    #pragma unroll
    for (int ox = 0; ox < TW; ++ox)
        os[(oy * TW + ox) * 66 + c] = acc[ox] / sum[ox];
    __syncthreads();
    #pragma unroll
    for (int i2 = 0; i2 < 4; ++i2) {
        int idx = t + i2 * 256;
        int p = idx & 15, cc = idx >> 4;
        out[(b * CH + cc) * PIX + (ty0 + (p >> 2)) * HW + tx0 + (p & 3)] =
            os[p * 66 + cc];
    }
}

// ---------------- Fallback: naive fused kernel (if ws too small) -------------
__global__ __launch_bounds__(256) void naive_kernel(
    const float* __restrict__ x,  const float* __restrict__ Wq,
    const float* __restrict__ Wk, const float* __restrict__ Wv,
    const float* __restrict__ rel_h, const float* __restrict__ rel_w,
    float* __restrict__ out)
{
    int idx = blockIdx.x * 256 + threadIdx.x;
    if (idx >= BATCH * CH * PIX) return;
    int wpx = idx % HW;
    int hpx = (idx / HW) % HW;
    int c   = (idx / PIX) % CH;
    int b   = idx / (PIX * CH);
    const float* xb = x + (size_t)b * CH * PIX;

    float q = 0.f;
    for (int ci = 0; ci < CH; ++ci)
        q += Wq[c * CH + ci] * xb[ci * PIX + hpx * HW + wpx];

    float sum = 0.f, acc = 0.f;
    #pragma unroll
    for (int kh = 0; kh < KS; ++kh)
        #pragma unroll
        for (int kw = 0; kw < KS; ++kw) {
            int y = hpx + kh - PAD, xx = wpx + kw - PAD;
            float kv = 0.f, vv = 0.f;
            if (y >= 0 && y < HW && xx >= 0 && xx < HW)
                for (int ci = 0; ci < CH; ++ci) {
                    float xvv = xb[ci * PIX + y * HW + xx];
                    kv += Wk[c * CH + ci] * xvv;
                    vv += Wv[c * CH + ci] * xvv;
                }
            vv += (c < 32) ? rel_h[c * KS + kh] : rel_w[(c - 32) * KS + kw];
            float e = __expf(q * kv);
            sum += e;
            acc += e * vv;
        }
    out[idx] = acc / sum;
}

extern "C" void kernel_launch(void* const* d_in, const int* in_sizes, int n_in,
                              void* d_out, int out_size, void* d_ws, size_t ws_size,
                              hipStream_t stream) {
    const float* x     = (const float*)d_in[0];
    const float* Wq    = (const float*)d_in[1];
    const float* Wk    = (const float*)d_in[2];
    const float* Wv    = (const float*)d_in[3];
    const float* rel_h = (const float*)d_in[4];
    const float* rel_w = (const float*)d_in[5];
    float* out = (float*)d_out;

    const size_t arr  = (size_t)NPIX * CH;             // 802816 floats
    const size_t need = 3 * arr * sizeof(float);       // ~9.6 MB

    if (ws_size >= need) {
        float* qg = (float*)d_ws;
        float* kg = qg + arr;
        float* vg = kg + arr;
        qkv_mfma<<<196, 256, 0, stream>>>(x, Wq, Wk, Wv, qg, kg, vg);
        attn_kernel<<<784, 256, 0, stream>>>(qg, kg, vg, rel_h, rel_w, out);
    } else {
        naive_kernel<<<(BATCH * CH * PIX + 255) / 256, 256, 0, stream>>>(
            x, Wq, Wk, Wv, rel_h, rel_w, out);
    }
}

// Round 4
// 35.061 us; speedup vs baseline: 2.2299x; 1.2617x over previous
//
#include <hip/hip_runtime.h>
#include <stdint.h>

#define HW   56
#define CH   64
#define PIX  (HW*HW)       // 3136
#define KS   7
#define PAD  3
#define TS   8             // 8x8 output tile
#define HALO 14            // TS + 2*PAD
#define HP   (HALO*HALO)   // 196 conv pixels per block
#define NPT  13            // ceil(196/16) MFMA px-tiles (rows 196..207 garbage, discarded)
#define XS_LD 65           // fp32 stride (65 == 1 mod 32 -> conflict-free)
#define KV_LD 66           // float2 stride

typedef __attribute__((ext_vector_type(8))) short short8;
typedef __attribute__((ext_vector_type(4))) float f32x4;

__device__ __forceinline__ uint32_t rne_bf16(float v) {
    uint32_t u = __float_as_uint(v);
    return (u + 0x7FFFu + ((u >> 16) & 1u)) >> 16;
}
__device__ __forceinline__ void split_bf16(float v, short& hi, short& lo) {
    uint32_t h = rne_bf16(v);
    float hf = __uint_as_float(h << 16);
    hi = (short)h;
    lo = (short)rne_bf16(v - hf);
}

// ---------------- fully fused: qkv conv (split-bf16 MFMA) + attention -------
// grid 196 = 4 b * 49 tiles, block 512 (8 waves).
__global__ __launch_bounds__(512) void fused_attn(
    const float* __restrict__ x,  const float* __restrict__ Wq,
    const float* __restrict__ Wk, const float* __restrict__ Wv,
    const float* __restrict__ rel_h, const float* __restrict__ rel_w,
    float* __restrict__ out)
{
    __shared__ float  xs[208 * XS_LD];     // 54,080 B: x halo, later q, per-px [p][ci]
    __shared__ float2 kvs[HP * KV_LD];     // 103,488 B: {k,v}, later output transpose

    const int t    = threadIdx.x;
    const int b    = blockIdx.x / 49;
    const int tile = blockIdx.x % 49;
    const int ty0  = (tile / 7) * TS;
    const int tx0  = (tile % 7) * TS;

    // ---- phase 1: stage x halo (fp32, coalesced 56B row reads) ----
    {
        const int lane16 = t & 15;         // hx (0..13 valid)
        const int unit   = t >> 4;         // 0..31 (job = (hy,ci) row)
        if (lane16 < HALO) {
            const int gx = tx0 + lane16 - PAD;
            const bool okx = (gx >= 0) & (gx < HW);
            #pragma unroll
            for (int k = 0; k < 28; ++k) {
                int u  = unit + 32 * k;    // 0..895
                int hy = u >> 6;           // 0..13
                int ci = u & 63;
                int gy = ty0 + hy - PAD;
                bool ok = okx & (gy >= 0) & (gy < HW);
                float v = 0.f;
                if (ok) v = x[(b * CH + ci) * PIX + gy * HW + gx];
                xs[(hy * HALO + lane16) * XS_LD + ci] = v;
            }
        }
    }
    __syncthreads();

    // ---- phase 2: per-wave A fragments (x as split bf16) into registers ----
    const int l    = t & 63;
    const int w    = t >> 6;               // wave 0..7
    const int lr   = l & 15;
    const int lk   = l >> 4;               // 0..3
    const int koff = lk * 8;

    short8 aH[2][2], aL[2][2];             // [tile slot][k-chunk]
    #pragma unroll
    for (int i = 0; i < 2; ++i) {
        int pt = w + 8 * i;
        if (pt < NPT) {
            int arow = pt * 16 + lr;       // <= 207
            #pragma unroll
            for (int ch = 0; ch < 2; ++ch) {
                short8 h, lo;
                #pragma unroll
                for (int j = 0; j < 8; ++j) {
                    float v = xs[arow * XS_LD + ch * 32 + koff + j];
                    short hh, ll;
                    split_bf16(v, hh, ll);
                    h[j] = hh; lo[j] = ll;
                }
                aH[i][ch] = h; aL[i][ch] = lo;
            }
        }
    }
    __syncthreads();   // xs reads done; q may now overwrite xs

    // ---- phase 3: k, v, q via MFMA (k->kvs.x, v->kvs.y, q->xs) ----
    #pragma unroll
    for (int m = 0; m < 3; ++m) {
        const float* __restrict__ Wm = (m == 0) ? Wk : (m == 1) ? Wv : Wq;
        short8 bH[4][2], bL[4][2];
        #pragma unroll
        for (int cot = 0; cot < 4; ++cot) {
            int bco = cot * 16 + lr;
            #pragma unroll
            for (int ch = 0; ch < 2; ++ch) {
                const float* p = &Wm[bco * 64 + ch * 32 + koff];
                float4 f0 = *(const float4*)p;
                float4 f1 = *(const float4*)(p + 4);
                short8 h, lo; short hh, ll;
                split_bf16(f0.x, hh, ll); h[0] = hh; lo[0] = ll;
                split_bf16(f0.y, hh, ll); h[1] = hh; lo[1] = ll;
                split_bf16(f0.z, hh, ll); h[2] = hh; lo[2] = ll;
                split_bf16(f0.w, hh, ll); h[3] = hh; lo[3] = ll;
                split_bf16(f1.x, hh, ll); h[4] = hh; lo[4] = ll;
                split_bf16(f1.y, hh, ll); h[5] = hh; lo[5] = ll;
                split_bf16(f1.z, hh, ll); h[6] = hh; lo[6] = ll;
                split_bf16(f1.w, hh, ll); h[7] = hh; lo[7] = ll;
                bH[cot][ch] = h; bL[cot][ch] = lo;
            }
        }
        #pragma unroll
        for (int i = 0; i < 2; ++i) {
            int pt = w + 8 * i;
            if (pt < NPT) {
                #pragma unroll
                for (int cot = 0; cot < 4; ++cot) {
                    f32x4 a = {0.f, 0.f, 0.f, 0.f};
                    a = __builtin_amdgcn_mfma_f32_16x16x32_bf16(aL[i][0], bH[cot][0], a, 0, 0, 0);
                    a = __builtin_amdgcn_mfma_f32_16x16x32_bf16(aH[i][0], bL[cot][0], a, 0, 0, 0);
                    a = __builtin_amdgcn_mfma_f32_16x16x32_bf16(aH[i][0], bH[cot][0], a, 0, 0, 0);
                    a = __builtin_amdgcn_mfma_f32_16x16x32_bf16(aL[i][1], bH[cot][1], a, 0, 0, 0);
                    a = __builtin_amdgcn_mfma_f32_16x16x32_bf16(aH[i][1], bL[cot][1], a, 0, 0, 0);
                    a = __builtin_amdgcn_mfma_f32_16x16x32_bf16(aH[i][1], bH[cot][1], a, 0, 0, 0);
                    const int co = cot * 16 + lr;
                    #pragma unroll
                    for (int r = 0; r < 4; ++r) {
                        int px = pt * 16 + lk * 4 + r;
                        if (px < HP) {
                            if (m == 0)      kvs[px * KV_LD + co].x = a[r];
                            else if (m == 1) kvs[px * KV_LD + co].y = a[r];
                            else             xs[px * XS_LD + co]    = a[r];
                        }
                    }
                }
            }
        }
    }
    __syncthreads();

    // ---- phase 4: per-channel windowed attention ----
    const int c  = t & 63;
    const int oy = t >> 6;                 // 0..7
    const bool is_h = (c < 32);
    float relv[KS];
    #pragma unroll
    for (int j = 0; j < KS; ++j)
        relv[j] = is_h ? rel_h[c * KS + j] : rel_w[(c - 32) * KS + j];

    float qv[TS], sum[TS], acc[TS];
    #pragma unroll
    for (int ox = 0; ox < TS; ++ox) {
        qv[ox] = xs[((oy + PAD) * HALO + ox + PAD) * XS_LD + c];
        sum[ox] = 0.f; acc[ox] = 0.f;
    }

    for (int kh = 0; kh < KS; ++kh) {
        float2 row[HALO];                  // halo row once, reused by 8 ox
        #pragma unroll
        for (int ii = 0; ii < HALO; ++ii)
            row[ii] = kvs[((oy + kh) * HALO + ii) * KV_LD + c];
        const float rh = relv[kh];
        #pragma unroll
        for (int ox = 0; ox < TS; ++ox) {
            #pragma unroll
            for (int kw = 0; kw < KS; ++kw) {
                float2 f = row[ox + kw];
                float e = __expf(qv[ox] * f.x);
                sum[ox] += e;
                acc[ox] = fmaf(e, f.y + (is_h ? rh : relv[kw]), acc[ox]);
            }
        }
    }

    // ---- phase 5: LDS transpose + coalesced BCHW store ----
    __syncthreads();                       // all kvs reads done
    float* os = (float*)&kvs[0];
    #pragma unroll
    for (int ox = 0; ox < TS; ++ox)
        os[(oy * TS + ox) * XS_LD + c] = acc[ox] / sum[ox];
    __syncthreads();
    #pragma unroll
    for (int k = 0; k < 8; ++k) {
        int idx = t + 512 * k;             // 0..4095
        int p   = idx & 63;
        int cc  = idx >> 6;
        out[(b * CH + cc) * PIX + (ty0 + (p >> 3)) * HW + tx0 + (p & 7)] =
            os[p * XS_LD + cc];
    }
}

extern "C" void kernel_launch(void* const* d_in, const int* in_sizes, int n_in,
                              void* d_out, int out_size, void* d_ws, size_t ws_size,
                              hipStream_t stream) {
    const float* x     = (const float*)d_in[0];
    const float* Wq    = (const float*)d_in[1];
    const float* Wk    = (const float*)d_in[2];
    const float* Wv    = (const float*)d_in[3];
    const float* rel_h = (const float*)d_in[4];
    const float* rel_w = (const float*)d_in[5];
    float* out = (float*)d_out;

    fused_attn<<<196, 512, 0, stream>>>(x, Wq, Wk, Wv, rel_h, rel_w, out);
}